// Round 3
// baseline (309.318 us; speedup 1.0000x reference)
//
#include <hip/hip_runtime.h>
#include <stdint.h>
#include <math.h>

#define S_LEN 2048
#define DMODEL 1024
#define NHEAD 16
#define DHEAD 64
#define BATCH 4
#define MROWS (BATCH * S_LEN) // 8192

typedef __attribute__((ext_vector_type(8))) short bf16x8;
typedef __attribute__((ext_vector_type(4))) float f32x4;

#define MFMA16(a, b, c) __builtin_amdgcn_mfma_f32_16x16x32_bf16(a, b, c, 0, 0, 0)

__device__ __forceinline__ unsigned short f2b(float f) {
  union { float f; unsigned u; } v; v.f = f;
  unsigned u = v.u;
  return (unsigned short)((u + 0x7FFFu + ((u >> 16) & 1u)) >> 16);
}
// pack two f32 -> bf16x2, round-half-up: 2 adds + 1 v_perm
__device__ __forceinline__ unsigned pkrn(float a, float b) {
  unsigned ua = __float_as_uint(a) + 0x8000u;
  unsigned ub = __float_as_uint(b) + 0x8000u;
  return __builtin_amdgcn_perm(ub, ua, 0x07060302);
}

// async global->LDS, 16B per lane; LDS dest = uniform base + lane*16
__device__ __forceinline__ void async16(const void* g, void* l) {
  __builtin_amdgcn_global_load_lds((const __attribute__((address_space(1))) void*)g,
                                   (__attribute__((address_space(3))) void*)l,
                                   16, 0, 0);
}

#define BAR() __builtin_amdgcn_s_barrier()
// rule #18: inline-asm lgkmcnt must be followed by sched_barrier(0) so the
// compiler cannot hoist register-only MFMAs above the wait.
#define LGKM0()                                        \
  do {                                                 \
    asm volatile("s_waitcnt lgkmcnt(0)" ::: "memory"); \
    __builtin_amdgcn_sched_barrier(0);                 \
  } while (0)
#define VMC2() asm volatile("s_waitcnt vmcnt(2)" ::: "memory")
#define VMC0() asm volatile("s_waitcnt vmcnt(0)" ::: "memory")

// ---------------- fused prep: f32->bf16 cvt (Xb) + 4x 1024x1024 transpose ---
struct PrepArgs {
  const float4* x; unsigned short* xb; int n4; int cvtBlocks;
  const float* s[4]; unsigned short* d[4];
};
__global__ __launch_bounds__(256) void prep_kernel(PrepArgs p) {
  __shared__ float T[64][65];
  const int bid = blockIdx.x;
  const int t = threadIdx.x;
  if (bid < p.cvtBlocks) {
    int i = bid * 256 + t;
    if (i < p.n4) {
      float4 v = p.x[i];
      ushort4 o;
      o.x = f2b(v.x); o.y = f2b(v.y); o.z = f2b(v.z); o.w = f2b(v.w);
      *(ushort4*)(p.xb + 4 * (size_t)i) = o;
    }
    return;
  }
  const int tb = bid - p.cvtBlocks;
  const int z = tb >> 8;
  const int rem = tb & 255;
  const int r0 = (rem >> 4) * 64, c0 = (rem & 15) * 64;
  const float* in = p.s[z];
  unsigned short* out = p.d[z];
  int c = t & 63, rr = t >> 6;
#pragma unroll
  for (int i = 0; i < 16; i++) {
    int r = i * 4 + rr;
    T[r][c] = in[(size_t)(r0 + r) * 1024 + c0 + c];
  }
  __syncthreads();
  int r2 = t & 63, cc = t >> 6;
#pragma unroll
  for (int i = 0; i < 16; i++) {
    int c2 = i * 4 + cc;
    out[(size_t)(c0 + c2) * 1024 + r0 + r2] = f2b(T[r2][c2]);
  }
}

// ---------------- fused QKV GEMM, 256^2 8-phase (T2+T3+T4+T5) ---------------
// C[8192,3072] = Xb * Wqkv^T; epilogue: Q->rope*scale, K->rope, V->transposed.
// 512 thr / 8 waves (2M x 4N), per-wave 128x64, acc[8][4], BK=64.
// LDS 128KB: As/Bs[2][256x64], raw s_barrier (no vmcnt(0) drain in main loop).
// Per K-tile: 4 phases x {stage 1 half-tile, ds-read subtile, bar, lgkm0,
// setprio(1), 16 MFMA, setprio(0), bar}; vmcnt(2) once per tile at P4.
// Half-tile schedule: HT_t = {A0,A1,B0,B1} staged at P4(t-2),P1..P3(t-1);
// at P4(t): <=10 loads outstanding/wave, vmcnt(2) retires the oldest 8 =
// exactly tile t+1's four half-tiles. WAR safety: P4's stage into the
// CURRENT buffer is ordered after every wave's P3 lgkmcnt(0) via the P3-exit
// barrier.
#define MFMA_QUAD(MB, NB)                                                     \
  do {                                                                        \
    _Pragma("unroll") for (int mi = 0; mi < 4; mi++)                          \
      _Pragma("unroll") for (int ni = 0; ni < 2; ni++) {                      \
        acc[(MB) + mi][(NB) + ni] =                                           \
            MFMA16(af[mi][0], bfr[(NB) + ni][0], acc[(MB) + mi][(NB) + ni]);  \
        acc[(MB) + mi][(NB) + ni] =                                           \
            MFMA16(af[mi][1], bfr[(NB) + ni][1], acc[(MB) + mi][(NB) + ni]);  \
      }                                                                       \
  } while (0)

__global__ __launch_bounds__(512, 2) void gemm_qkv(const unsigned short* __restrict__ A,
                                                   const unsigned short* __restrict__ Bt,
                                                   unsigned short* __restrict__ Qr,
                                                   unsigned short* __restrict__ Kr,
                                                   unsigned short* __restrict__ Vt,
                                                   const int* __restrict__ pos) {
  constexpr int K = 1024, NT = 16;
  __shared__ unsigned short As[2][256 * 64];
  __shared__ unsigned short Bs[2][256 * 64];
  // bijective XCD swizzle (384 % 8 == 0): each XCD gets 4 full M-rows of tiles
  const int bid = blockIdx.x;
  const int sw = (bid & 7) * 48 + (bid >> 3);
  const int bm = (sw / 12) * 256, bn = (sw % 12) * 256;
  const int t = threadIdx.x;
  const int wave = t >> 6, lane = t & 63, quad = lane >> 4, l16 = lane & 15;
  const int wr = wave >> 2, wc = wave & 3; // 2M x 4N
  const int srow = lane >> 3;
  const int gcol = ((lane & 7) ^ srow) * 8; // XOR-swizzled source column
  const int rsw8 = l16 & 7;
  f32x4 acc[8][4] = {};

  auto stage_half = [&](int tt, int h) {
    // h: 0=A rows[0,128), 1=A rows[128,256), 2=B rows[0,128), 3=B rows[128,256)
    const int b = tt & 1;
    const int k0 = tt * 64;
    const int hr = (h & 1) * 128;
    if (h < 2) {
      const unsigned short* G = A + (size_t)(bm + hr + wave * 8 + srow) * K + k0 + gcol;
      unsigned short* L = &As[b][(hr + wave * 8) * 64];
      async16(G, L);
      async16(G + (size_t)64 * K, L + 64 * 64);
    } else {
      const unsigned short* G = Bt + (size_t)(bn + hr + wave * 8 + srow) * K + k0 + gcol;
      unsigned short* L = &Bs[b][(hr + wave * 8) * 64];
      async16(G, L);
      async16(G + (size_t)64 * K, L + 64 * 64);
    }
  };
  auto ldA = [&](const unsigned short* Ab, int m, int kk) -> bf16x8 {
    return *(const bf16x8*)&Ab[(wr * 128 + m * 16 + l16) * 64 +
                               (((kk * 4 + quad) ^ rsw8) << 3)];
  };
  auto ldB = [&](const unsigned short* Bb, int n, int kk) -> bf16x8 {
    return *(const bf16x8*)&Bb[(wc * 64 + n * 16 + l16) * 64 +
                               (((kk * 4 + quad) ^ rsw8) << 3)];
  };

  auto ktile = [&](int tt, int smode) {
    // smode: 2 = steady (stage t+1[1..3], t+2[0], vmcnt(2));
    //        1 = tail-1 (stage t+1[1..3], vmcnt(0)); 0 = last (no stage).
    const int b = tt & 1;
    const unsigned short* Ab = &As[b][0];
    const unsigned short* Bb = &Bs[b][0];
    bf16x8 af[4][2], bfr[4][2];
    // P1: A m0-3, B n0-1 (12 ds_reads); MFMA m0-3 x n0-1
    if (smode) stage_half(tt + 1, 1);
#pragma unroll
    for (int mi = 0; mi < 4; mi++) {
      af[mi][0] = ldA(Ab, mi, 0); af[mi][1] = ldA(Ab, mi, 1);
    }
#pragma unroll
    for (int ni = 0; ni < 2; ni++) {
      bfr[ni][0] = ldB(Bb, ni, 0); bfr[ni][1] = ldB(Bb, ni, 1);
    }
    BAR(); LGKM0();
    __builtin_amdgcn_s_setprio(1);
    MFMA_QUAD(0, 0);
    __builtin_amdgcn_s_setprio(0);
    BAR();
    // P2: B n2-3 (4 reads); MFMA m0-3 x n2-3
    if (smode) stage_half(tt + 1, 2);
#pragma unroll
    for (int ni = 0; ni < 2; ni++) {
      bfr[2 + ni][0] = ldB(Bb, 2 + ni, 0); bfr[2 + ni][1] = ldB(Bb, 2 + ni, 1);
    }
    BAR(); LGKM0();
    __builtin_amdgcn_s_setprio(1);
    MFMA_QUAD(0, 2);
    __builtin_amdgcn_s_setprio(0);
    BAR();
    // P3: A m4-7 (8 reads, reuse af regs); MFMA m4-7 x n2-3
    if (smode) stage_half(tt + 1, 3);
#pragma unroll
    for (int mi = 0; mi < 4; mi++) {
      af[mi][0] = ldA(Ab, 4 + mi, 0); af[mi][1] = ldA(Ab, 4 + mi, 1);
    }
    BAR(); LGKM0();
    __builtin_amdgcn_s_setprio(1);
    MFMA_QUAD(4, 2);
    __builtin_amdgcn_s_setprio(0);
    BAR();
    // P4: no reads; MFMA m4-7 x n0-1; counted vmcnt for next tile
    if (smode == 2) stage_half(tt + 2, 0);
    BAR();
    __builtin_amdgcn_s_setprio(1);
    MFMA_QUAD(4, 0);
    __builtin_amdgcn_s_setprio(0);
    if (smode == 2) { VMC2(); } else if (smode == 1) { VMC0(); }
    BAR();
  };

  // prologue: tile0 complete + HT1[0] in flight (10 loads, wait 8)
  stage_half(0, 0); stage_half(0, 1); stage_half(0, 2); stage_half(0, 3);
  stage_half(1, 0);
  VMC2(); BAR();

  for (int tt = 0; tt < NT - 2; ++tt) ktile(tt, 2);
  ktile(NT - 2, 1);
  ktile(NT - 1, 0);

  // ---------------- epilogue (per-wave column span = one 64-col head) -------
  const int cb = bn + wc * 64;
  if (cb >= 2048) {
    // V: write directly transposed [b,h,dh,s]
    const int h = (cb - 2048) >> 6;
#pragma unroll
    for (int mt = 0; mt < 8; mt++)
#pragma unroll
      for (int nt = 0; nt < 4; nt++) {
        int row = bm + wr * 128 + mt * 16 + quad * 4;
        int b = row >> 11, s = row & (S_LEN - 1);
        int dh = nt * 16 + l16;
        ushort4 w4;
        w4.x = f2b(acc[mt][nt][0]); w4.y = f2b(acc[mt][nt][1]);
        w4.z = f2b(acc[mt][nt][2]); w4.w = f2b(acc[mt][nt][3]);
        *(ushort4*)&Vt[((size_t)(b * NHEAD + h) * DHEAD + dh) * S_LEN + s] = w4;
      }
  } else {
    const bool isQ = cb < 1024;
    unsigned short* dst0 = isQ ? Qr : Kr;
    const float scl = isQ ? 0.18033688011112042f : 1.0f; // 0.125*log2(e) for Q
    const int h = (cb >> 6) & 15;
    const float LT = 0.28782313662425572f; // ln(10000)/32
    float it0 = __expf(-(float)l16 * LT);
    float it1 = __expf(-(float)(16 + l16) * LT);
#pragma unroll
    for (int mt = 0; mt < 8; mt++) {
#pragma unroll
      for (int r = 0; r < 4; r++) {
        int row = bm + wr * 128 + mt * 16 + quad * 4 + r;
        int b = row >> 11, s = row & (S_LEN - 1);
        float p = (float)pos[row];
        float a0 = p * it0, a1 = p * it1;
        float sn0 = __sinf(a0), cs0 = __cosf(a0);
        float sn1 = __sinf(a1), cs1 = __cosf(a1);
        float x0 = acc[mt][0][r], x1 = acc[mt][1][r];
        float x2 = acc[mt][2][r], x3 = acc[mt][3][r];
        float o0 = (x0 * cs0 - x2 * sn0) * scl;
        float o2 = (x2 * cs0 + x0 * sn0) * scl;
        float o1 = (x1 * cs1 - x3 * sn1) * scl;
        float o3 = (x3 * cs1 + x1 * sn1) * scl;
        unsigned short* dst =
            dst0 + ((size_t)(b * NHEAD + h) * S_LEN + s) * DHEAD;
        dst[0 * 16 + l16] = f2b(o0);
        dst[1 * 16 + l16] = f2b(o1);
        dst[2 * 16 + l16] = f2b(o2);
        dst[3 * 16 + l16] = f2b(o3);
      }
    }
  }
}

// ---------------- out-proj GEMM: out[8192,1024] f32 = Xat * WoT^T -----------
__global__ __launch_bounds__(256) void gemm_out(const unsigned short* __restrict__ A,
                                                const unsigned short* __restrict__ Bt,
                                                float* __restrict__ C) {
  constexpr int K = 1024, N = 1024;
  __shared__ unsigned short As[128 * 64];
  __shared__ unsigned short Bs[128 * 64];
  const int bm = blockIdx.y * 128, bn = blockIdx.x * 128;
  const int t = threadIdx.x;
  const int wave = t >> 6, lane = t & 63, quad = lane >> 4, l16 = lane & 15;
  const int wm = (wave >> 1) * 64, wn = (wave & 1) * 64;
  f32x4 acc[4][4] = {};
  const int srow = lane >> 3;
  const int gcol = (((lane & 7) ^ srow)) * 8;
  const unsigned short* Ag = A + (size_t)(bm + wave * 32 + srow) * K + gcol;
  const unsigned short* Bg = Bt + (size_t)(bn + wave * 32 + srow) * K + gcol;
  unsigned short* AsW = &As[(wave * 32) * 64];
  unsigned short* BsW = &Bs[(wave * 32) * 64];
  const int rsw = l16 & 7;

  for (int k0 = 0; k0 < K; k0 += 64) {
    __syncthreads();
#pragma unroll
    for (int i = 0; i < 4; i++) {
      async16(Ag + (size_t)(i * 8) * K + k0, AsW + i * 8 * 64);
      async16(Bg + (size_t)(i * 8) * K + k0, BsW + i * 8 * 64);
    }
    __syncthreads();
#pragma unroll
    for (int kk = 0; kk < 2; kk++) {
      const int sl = ((kk * 4 + quad) ^ rsw) << 3;
      bf16x8 af[4], bfr[4];
#pragma unroll
      for (int mt = 0; mt < 4; mt++)
        af[mt] = *(const bf16x8*)&As[(wm + mt * 16 + l16) * 64 + sl];
#pragma unroll
      for (int nt = 0; nt < 4; nt++)
        bfr[nt] = *(const bf16x8*)&Bs[(wn + nt * 16 + l16) * 64 + sl];
#pragma unroll
      for (int mt = 0; mt < 4; mt++)
#pragma unroll
        for (int nt = 0; nt < 4; nt++)
          acc[mt][nt] = MFMA16(af[mt], bfr[nt], acc[mt][nt]);
    }
  }
#pragma unroll
  for (int mt = 0; mt < 4; mt++)
#pragma unroll
    for (int nt = 0; nt < 4; nt++)
#pragma unroll
      for (int r = 0; r < 4; r++) {
        int row = bm + wm + mt * 16 + quad * 4 + r;
        int col = bn + wn + nt * 16 + l16;
        C[(size_t)row * N + col] = acc[mt][nt][r];
      }
}

// ---------------- flash attention: 128 q-rows/block (two 64-row halves) -----
// Adjacent-pairing version (R0, 73us). R1's uniform-work (j,31-j) pairing
// REGRESSED to 87us: it equalized per-CU compute but raised staged-tile count
// 272->392 per bh (+44%); per-stage overhead (barrier + load drain) dominates,
// so shared-tile reuse (every staged tile feeds both halves) beats balance.
__global__ __launch_bounds__(256, 3) void flash_kernel(const unsigned short* __restrict__ Qr,
                                                       const unsigned short* __restrict__ Kr,
                                                       const unsigned short* __restrict__ Vt,
                                                       unsigned short* __restrict__ Xat) {
  const int idx = blockIdx.x;        // 0..1023
  const int qt = 15 - (idx >> 6);    // LPT: longest first
  const int bh = idx & 63;
  const unsigned short* Qh = Qr + (size_t)bh * S_LEN * DHEAD;
  const unsigned short* Kh = Kr + (size_t)bh * S_LEN * DHEAD;
  const unsigned short* Vh = Vt + (size_t)bh * DHEAD * S_LEN;
  __shared__ unsigned short Ks[2][64 * 64]; // [kcol][dh], XOR-swizzled slots
  __shared__ unsigned short Vs[2][64 * 64]; // [dh][kcol], XOR-swizzled slots
  __shared__ unsigned short Pt[4][16 * 64]; // per-wave P^T [q][k], swizzled
  const int t = threadIdx.x, wave = t >> 6, lane = t & 63;
  const int quad = lane >> 4, l16 = lane & 15;
  const int srow = lane >> 3;
  const int gcol = (((lane & 7) ^ srow)) * 8;
  const int rsw = l16 & 7;
  const int q0 = qt * 128;
  const int qrA = q0 + wave * 16 + l16;  // half A row
  const int qrB = qrA + 64;              // half B row

  bf16x8 qfA0 = *(const bf16x8*)(Qh + (size_t)qrA * DHEAD + quad * 8);
  bf16x8 qfA1 = *(const bf16x8*)(Qh + (size_t)qrA * DHEAD + 32 + quad * 8);
  bf16x8 qfB0 = *(const bf16x8*)(Qh + (size_t)qrB * DHEAD + quad * 8);
  bf16x8 qfB1 = *(const bf16x8*)(Qh + (size_t)qrB * DHEAD + 32 + quad * 8);

  f32x4 oA[4] = {}, oB[4] = {};
  float lA = 0.f, lB = 0.f;
  unsigned short* PtW = &Pt[wave][0];
  const int c0 = (quad ^ rsw) << 3;        // kk=0 frag slot
  const int c1 = ((4 + quad) ^ rsw) << 3;  // kk=1 frag slot
  const int q1b = quad >> 1, qlo4 = (quad & 1) * 4;
  const int pr = l16 * 64;

  auto stage = [&](int kt, int buf) {
    const int k0 = kt * 64;
#pragma unroll
    for (int i = 0; i < 2; i++) {
      async16(Kh + (size_t)(k0 + wave * 16 + i * 8 + srow) * DHEAD + gcol,
              &Ks[buf][(wave * 16 + i * 8) * 64]);
      async16(Vh + (size_t)(wave * 16 + i * 8 + srow) * S_LEN + k0 + gcol,
              &Vs[buf][(wave * 16 + i * 8) * 64]);
    }
  };

  // softmax (no running max: scores bounded) + P^T pack + PV accumulate
  auto softpv = [&](const unsigned short* V_, f32x4* sc, f32x4* o, float& l,
                    int qr_, bool diag, int k0) {
#pragma unroll
    for (int nt = 0; nt < 4; nt++) {
      float p0, p1, p2, p3;
      if (diag) {
        int kg = k0 + nt * 16 + quad * 4;
        p0 = (kg + 0 > qr_) ? 0.f : exp2f(sc[nt][0]);
        p1 = (kg + 1 > qr_) ? 0.f : exp2f(sc[nt][1]);
        p2 = (kg + 2 > qr_) ? 0.f : exp2f(sc[nt][2]);
        p3 = (kg + 3 > qr_) ? 0.f : exp2f(sc[nt][3]);
      } else {
        p0 = exp2f(sc[nt][0]);
        p1 = exp2f(sc[nt][1]);
        p2 = exp2f(sc[nt][2]);
        p3 = exp2f(sc[nt][3]);
      }
      l += (p0 + p1) + (p2 + p3);
      uint2 w; w.x = pkrn(p0, p1); w.y = pkrn(p2, p3);
      const int slot = ((nt * 2 + q1b) ^ rsw) << 3; // nt literal; XOR != dist over +
      *(uint2*)&PtW[pr + slot + qlo4] = w;
    }
#pragma unroll
    for (int kk = 0; kk < 2; kk++) {
      bf16x8 pb = *(const bf16x8*)&PtW[pr + (((kk * 4 + quad) ^ rsw) << 3)];
#pragma unroll
      for (int nt = 0; nt < 4; nt++) {
        bf16x8 vb = *(const bf16x8*)&V_[(nt * 16 + l16) * 64 + (kk == 0 ? c0 : c1)];
        o[nt] = MFMA16(vb, pb, o[nt]);
      }
    }
  };

  // both halves against one tile; K-frags read once from LDS
  auto computeAB = [&](int cur, int k0, bool adiag) {
    const unsigned short* K_ = Ks[cur];
    const unsigned short* V_ = Vs[cur];
    f32x4 scA[4] = {}, scB[4] = {};
#pragma unroll
    for (int nt = 0; nt < 4; nt++) {
      bf16x8 kb0 = *(const bf16x8*)&K_[(nt * 16 + l16) * 64 + c0];
      bf16x8 kb1 = *(const bf16x8*)&K_[(nt * 16 + l16) * 64 + c1];
      scA[nt] = MFMA16(kb0, qfA0, scA[nt]);
      scA[nt] = MFMA16(kb1, qfA1, scA[nt]);
      scB[nt] = MFMA16(kb0, qfB0, scB[nt]);
      scB[nt] = MFMA16(kb1, qfB1, scB[nt]);
    }
    softpv(V_, scA, oA, lA, qrA, adiag, k0);
    softpv(V_, scB, oB, lB, qrB, false, k0);
  };

  stage(0, 0);
  const int kmax = 2 * qt; // A's diagonal tile index; B diag at kmax+1
  int kt = 0;
  for (; kt < kmax; kt += 2) {
    __syncthreads();
    stage(kt + 1, 1);
    computeAB(0, kt * 64, false);
    __syncthreads();
    stage(kt + 2, 0);
    computeAB(1, (kt + 1) * 64, false);
  }
  // kt == kmax (even), buf0 holds tile kmax
  __syncthreads();
  stage(kmax + 1, 1);
  computeAB(0, kmax * 64, true); // A diag-masked, B full
  __syncthreads();
  { // B diagonal tile (buf1): B only
    const unsigned short* K_ = Ks[1];
    const unsigned short* V_ = Vs[1];
    f32x4 scB[4] = {};
#pragma unroll
    for (int nt = 0; nt < 4; nt++) {
      bf16x8 kb0 = *(const bf16x8*)&K_[(nt * 16 + l16) * 64 + c0];
      bf16x8 kb1 = *(const bf16x8*)&K_[(nt * 16 + l16) * 64 + c1];
      scB[nt] = MFMA16(kb0, qfB0, scB[nt]);
      scB[nt] = MFMA16(kb1, qfB1, scB[nt]);
    }
    softpv(V_, scB, oB, lB, qrB, true, (kmax + 1) * 64);
  }

  lA += __shfl_xor(lA, 16); lA += __shfl_xor(lA, 32);
  lB += __shfl_xor(lB, 16); lB += __shfl_xor(lB, 32);
  const float ivA = 1.0f / lA, ivB = 1.0f / lB;
  const int b = bh >> 4, h = bh & 15;
  unsigned short* dA = Xat + (size_t)(b * S_LEN + qrA) * DMODEL + h * DHEAD;
  unsigned short* dB = Xat + (size_t)(b * S_LEN + qrB) * DMODEL + h * DHEAD;
#pragma unroll
  for (int nt = 0; nt < 4; nt++) {
    ushort4 wa, wb;
    wa.x = f2b(oA[nt][0] * ivA); wa.y = f2b(oA[nt][1] * ivA);
    wa.z = f2b(oA[nt][2] * ivA); wa.w = f2b(oA[nt][3] * ivA);
    wb.x = f2b(oB[nt][0] * ivB); wb.y = f2b(oB[nt][1] * ivB);
    wb.z = f2b(oB[nt][2] * ivB); wb.w = f2b(oB[nt][3] * ivB);
    *(ushort4*)(dA + nt * 16 + quad * 4) = wa;
    *(ushort4*)(dB + nt * 16 + quad * 4) = wb;
  }
}

extern "C" void kernel_launch(void* const* d_in, const int* in_sizes, int n_in,
                              void* d_out, int out_size, void* d_ws, size_t ws_size,
                              hipStream_t stream) {
  const float* x = (const float*)d_in[0];
  const float* wq = (const float*)d_in[1];
  const float* wk = (const float*)d_in[2];
  const float* wv = (const float*)d_in[3];
  const float* wo = (const float*)d_in[4];
  const int* pos = (const int*)d_in[5];
  float* out = (float*)d_out;
  char* ws = (char*)d_ws;

  const size_t EL_X = (size_t)MROWS * DMODEL; // 8M elements
  const size_t EL_W = (size_t)DMODEL * DMODEL;
  unsigned short* Xb = (unsigned short*)ws; // bf16 activations [M,K]
  unsigned short* Wqkv = Xb + EL_X;         // [3072][1024] stacked q,k,v
  unsigned short* WoT = Wqkv + 3 * EL_W;
  unsigned short* Qr = WoT + EL_W;  // [b,h,s,dh] roped, pre-scaled
  unsigned short* Kr = Qr + EL_X;   // [b,h,s,dh] roped
  unsigned short* Vt = Kr + EL_X;   // [b,h,dh,s]
  unsigned short* Xat = Vt + EL_X;  // [b,s,h,dh] attention output

  PrepArgs pa;
  pa.x = (const float4*)x; pa.xb = Xb;
  pa.n4 = (int)(EL_X / 4);
  pa.cvtBlocks = (int)(EL_X / 4 / 256); // 8192
  pa.s[0] = wq; pa.d[0] = Wqkv;
  pa.s[1] = wk; pa.d[1] = Wqkv + EL_W;
  pa.s[2] = wv; pa.d[2] = Wqkv + 2 * EL_W;
  pa.s[3] = wo; pa.d[3] = WoT;
  prep_kernel<<<pa.cvtBlocks + 1024, 256, 0, stream>>>(pa);

  gemm_qkv<<<384, 512, 0, stream>>>(Xb, Wqkv, Qr, Kr, Vt, pos);
  flash_kernel<<<1024, 256, 0, stream>>>(Qr, Kr, Vt, Xat);
  dim3 gg(8, 64);
  gemm_out<<<gg, 256, 0, stream>>>(Xat, WoT, out);
}

// Round 4
// 287.364 us; speedup vs baseline: 1.0764x; 1.0764x over previous
//
#include <hip/hip_runtime.h>
#include <stdint.h>
#include <math.h>

#define S_LEN 2048
#define DMODEL 1024
#define NHEAD 16
#define DHEAD 64
#define BATCH 4
#define MROWS (BATCH * S_LEN) // 8192

typedef __attribute__((ext_vector_type(8))) short bf16x8;
typedef __attribute__((ext_vector_type(4))) float f32x4;

#define MFMA16(a, b, c) __builtin_amdgcn_mfma_f32_16x16x32_bf16(a, b, c, 0, 0, 0)

__device__ __forceinline__ unsigned short f2b(float f) {
  union { float f; unsigned u; } v; v.f = f;
  unsigned u = v.u;
  return (unsigned short)((u + 0x7FFFu + ((u >> 16) & 1u)) >> 16);
}
// pack two f32 -> bf16x2, round-half-up: 2 adds + 1 v_perm
__device__ __forceinline__ unsigned pkrn(float a, float b) {
  unsigned ua = __float_as_uint(a) + 0x8000u;
  unsigned ub = __float_as_uint(b) + 0x8000u;
  return __builtin_amdgcn_perm(ub, ua, 0x07060302);
}

// async global->LDS, 16B per lane; LDS dest = uniform base + lane*16
__device__ __forceinline__ void async16(const void* g, void* l) {
  __builtin_amdgcn_global_load_lds((const __attribute__((address_space(1))) void*)g,
                                   (__attribute__((address_space(3))) void*)l,
                                   16, 0, 0);
}

// ---------------- fused prep: f32->bf16 cvt (Xb) + 4x 1024x1024 transpose ---
struct PrepArgs {
  const float4* x; unsigned short* xb; int n4; int cvtBlocks;
  const float* s[4]; unsigned short* d[4];
};
__global__ __launch_bounds__(256) void prep_kernel(PrepArgs p) {
  __shared__ float T[64][65];
  const int bid = blockIdx.x;
  const int t = threadIdx.x;
  if (bid < p.cvtBlocks) {
    int i = bid * 256 + t;
    if (i < p.n4) {
      float4 v = p.x[i];
      ushort4 o;
      o.x = f2b(v.x); o.y = f2b(v.y); o.z = f2b(v.z); o.w = f2b(v.w);
      *(ushort4*)(p.xb + 4 * (size_t)i) = o;
    }
    return;
  }
  const int tb = bid - p.cvtBlocks;
  const int z = tb >> 8;
  const int rem = tb & 255;
  const int r0 = (rem >> 4) * 64, c0 = (rem & 15) * 64;
  const float* in = p.s[z];
  unsigned short* out = p.d[z];
  int c = t & 63, rr = t >> 6;
#pragma unroll
  for (int i = 0; i < 16; i++) {
    int r = i * 4 + rr;
    T[r][c] = in[(size_t)(r0 + r) * 1024 + c0 + c];
  }
  __syncthreads();
  int r2 = t & 63, cc = t >> 6;
#pragma unroll
  for (int i = 0; i < 16; i++) {
    int c2 = i * 4 + cc;
    out[(size_t)(c0 + c2) * 1024 + r0 + r2] = f2b(T[r2][c2]);
  }
}

// ---------------- fused QKV GEMM: C[8192,3072] = Xb * Wqkv^T -----------------
// PROVEN 128^2 2-barrier structure (72.8us, 708 TF, MfmaUtil 29).
// R3's 256^2 8-phase port REGRESSED to 92us (MfmaUtil 21): naive port of the
// template puts every phase's ds_reads across all 4 half-tiles -> full-tile
// drain per tile + serialized LDS/MFMA. Per m152, the 8-phase combo needs the
// exact HK barrier/residency placement; do not re-attempt without the
// derived-waits port.
// cols [0,1024) Q->rope*(0.125*log2e) -> Qr[b,h,s,dh]
// cols [1024,2048) K->rope            -> Kr[b,h,s,dh]
// cols [2048,3072) V                  -> Vt[b,h,dh,s] (direct transposed)
__global__ __launch_bounds__(256) void gemm_qkv(const unsigned short* __restrict__ A,
                                                const unsigned short* __restrict__ Bt,
                                                unsigned short* __restrict__ Qr,
                                                unsigned short* __restrict__ Kr,
                                                unsigned short* __restrict__ Vt,
                                                const int* __restrict__ pos) {
  constexpr int K = 1024;
  __shared__ unsigned short As[128 * 64];
  __shared__ unsigned short Bs[128 * 64];
  const int bm = blockIdx.y * 128, bn = blockIdx.x * 128;
  const int t = threadIdx.x;
  const int wave = t >> 6, lane = t & 63, quad = lane >> 4, l16 = lane & 15;
  const int wm = (wave >> 1) * 64, wn = (wave & 1) * 64;
  f32x4 acc[4][4] = {};
  const int srow = lane >> 3;
  const int gcol = (((lane & 7) ^ srow)) * 8; // XOR-swizzled source column
  const unsigned short* Ag = A + (size_t)(bm + wave * 32 + srow) * K + gcol;
  const unsigned short* Bg = Bt + (size_t)(bn + wave * 32 + srow) * K + gcol;
  unsigned short* AsW = &As[(wave * 32) * 64];
  unsigned short* BsW = &Bs[(wave * 32) * 64];
  const int rsw = l16 & 7;

  for (int k0 = 0; k0 < K; k0 += 64) {
    __syncthreads();
#pragma unroll
    for (int i = 0; i < 4; i++) {
      async16(Ag + (size_t)(i * 8) * K + k0, AsW + i * 8 * 64);
      async16(Bg + (size_t)(i * 8) * K + k0, BsW + i * 8 * 64);
    }
    __syncthreads();
#pragma unroll
    for (int kk = 0; kk < 2; kk++) {
      const int sl = ((kk * 4 + quad) ^ rsw) << 3;
      bf16x8 af[4], bfr[4];
#pragma unroll
      for (int mt = 0; mt < 4; mt++)
        af[mt] = *(const bf16x8*)&As[(wm + mt * 16 + l16) * 64 + sl];
#pragma unroll
      for (int nt = 0; nt < 4; nt++)
        bfr[nt] = *(const bf16x8*)&Bs[(wn + nt * 16 + l16) * 64 + sl];
#pragma unroll
      for (int mt = 0; mt < 4; mt++)
#pragma unroll
        for (int nt = 0; nt < 4; nt++)
          acc[mt][nt] = MFMA16(af[mt], bfr[nt], acc[mt][nt]);
    }
  }

  const int cb = bn + wn;
  if (cb >= 2048) {
    // V: write directly transposed [b,h,dh,s]
    const int h = (cb - 2048) >> 6;
#pragma unroll
    for (int mt = 0; mt < 4; mt++)
#pragma unroll
      for (int nt = 0; nt < 4; nt++) {
        int row = bm + wm + mt * 16 + quad * 4;
        int b = row >> 11, s = row & (S_LEN - 1);
        int dh = nt * 16 + l16;
        ushort4 w4;
        w4.x = f2b(acc[mt][nt][0]); w4.y = f2b(acc[mt][nt][1]);
        w4.z = f2b(acc[mt][nt][2]); w4.w = f2b(acc[mt][nt][3]);
        *(ushort4*)&Vt[((size_t)(b * NHEAD + h) * DHEAD + dh) * S_LEN + s] = w4;
      }
  } else {
    const bool isQ = cb < 1024;
    unsigned short* dst0 = isQ ? Qr : Kr;
    const float scl = isQ ? 0.18033688011112042f : 1.0f; // 0.125*log2(e) for Q
    const int h = (cb >> 6) & 15;
    const float LT = 0.28782313662425572f; // ln(10000)/32
    float it0 = __expf(-(float)l16 * LT);
    float it1 = __expf(-(float)(16 + l16) * LT);
#pragma unroll
    for (int mt = 0; mt < 4; mt++) {
#pragma unroll
      for (int r = 0; r < 4; r++) {
        int row = bm + wm + mt * 16 + quad * 4 + r;
        int b = row >> 11, s = row & (S_LEN - 1);
        float p = (float)pos[row];
        // fast HW sin/cos: arg<=2047 rad, reduction error ~1e-4 << bf16
        // storage error. libm sincosf cost ~= the whole MFMA loop (R6).
        float a0 = p * it0, a1 = p * it1;
        float sn0 = __sinf(a0), cs0 = __cosf(a0);
        float sn1 = __sinf(a1), cs1 = __cosf(a1);
        float x0 = acc[mt][0][r], x1 = acc[mt][1][r];
        float x2 = acc[mt][2][r], x3 = acc[mt][3][r];
        float o0 = (x0 * cs0 - x2 * sn0) * scl;
        float o2 = (x2 * cs0 + x0 * sn0) * scl;
        float o1 = (x1 * cs1 - x3 * sn1) * scl;
        float o3 = (x3 * cs1 + x1 * sn1) * scl;
        unsigned short* dst =
            dst0 + ((size_t)(b * NHEAD + h) * S_LEN + s) * DHEAD;
        dst[0 * 16 + l16] = f2b(o0);
        dst[1 * 16 + l16] = f2b(o1);
        dst[2 * 16 + l16] = f2b(o2);
        dst[3 * 16 + l16] = f2b(o3);
      }
    }
  }
}

// ---------------- out-proj GEMM: out[8192,1024] f32 = Xat * WoT^T -----------
__global__ __launch_bounds__(256) void gemm_out(const unsigned short* __restrict__ A,
                                                const unsigned short* __restrict__ Bt,
                                                float* __restrict__ C) {
  constexpr int K = 1024, N = 1024;
  __shared__ unsigned short As[128 * 64];
  __shared__ unsigned short Bs[128 * 64];
  const int bm = blockIdx.y * 128, bn = blockIdx.x * 128;
  const int t = threadIdx.x;
  const int wave = t >> 6, lane = t & 63, quad = lane >> 4, l16 = lane & 15;
  const int wm = (wave >> 1) * 64, wn = (wave & 1) * 64;
  f32x4 acc[4][4] = {};
  const int srow = lane >> 3;
  const int gcol = (((lane & 7) ^ srow)) * 8;
  const unsigned short* Ag = A + (size_t)(bm + wave * 32 + srow) * K + gcol;
  const unsigned short* Bg = Bt + (size_t)(bn + wave * 32 + srow) * K + gcol;
  unsigned short* AsW = &As[(wave * 32) * 64];
  unsigned short* BsW = &Bs[(wave * 32) * 64];
  const int rsw = l16 & 7;

  for (int k0 = 0; k0 < K; k0 += 64) {
    __syncthreads();
#pragma unroll
    for (int i = 0; i < 4; i++) {
      async16(Ag + (size_t)(i * 8) * K + k0, AsW + i * 8 * 64);
      async16(Bg + (size_t)(i * 8) * K + k0, BsW + i * 8 * 64);
    }
    __syncthreads();
#pragma unroll
    for (int kk = 0; kk < 2; kk++) {
      const int sl = ((kk * 4 + quad) ^ rsw) << 3;
      bf16x8 af[4], bfr[4];
#pragma unroll
      for (int mt = 0; mt < 4; mt++)
        af[mt] = *(const bf16x8*)&As[(wm + mt * 16 + l16) * 64 + sl];
#pragma unroll
      for (int nt = 0; nt < 4; nt++)
        bfr[nt] = *(const bf16x8*)&Bs[(wn + nt * 16 + l16) * 64 + sl];
#pragma unroll
      for (int mt = 0; mt < 4; mt++)
#pragma unroll
        for (int nt = 0; nt < 4; nt++)
          acc[mt][nt] = MFMA16(af[mt], bfr[nt], acc[mt][nt]);
    }
  }
#pragma unroll
  for (int mt = 0; mt < 4; mt++)
#pragma unroll
    for (int nt = 0; nt < 4; nt++)
#pragma unroll
      for (int r = 0; r < 4; r++) {
        int row = bm + wm + mt * 16 + quad * 4 + r;
        int col = bn + wn + nt * 16 + l16;
        C[(size_t)row * N + col] = acc[mt][nt][r];
      }
}

// ---------------- flash attention: 128 q-rows/block (two 64-row halves) -----
// Adjacent pairing (shared-tile reuse: every staged K/V tile feeds BOTH
// halves). R1's (j,31-j) uniform-work pairing regressed (+44% staging).
// NEW (R4): balanced qt permutation. Under round-robin dispatch, block bid ->
// XCD bid%8, CU slot (bid/8)%32, so co-resident quads are {i,i+256,i+512,
// i+768} = j-classes {c,c+4,c+8,c+12}. Map qt(c,k) = {15-c,7-c,8+c,c}[k]:
// each class sums to 30 -> every CU gets exactly 68 tile-units (was 80..56,
// 1.43x imbalance with all blocks resident from t=0). Bijective on [0,16),
// staging volume identical to R0.
__global__ __launch_bounds__(256, 3) void flash_kernel(const unsigned short* __restrict__ Qr,
                                                       const unsigned short* __restrict__ Kr,
                                                       const unsigned short* __restrict__ Vt,
                                                       unsigned short* __restrict__ Xat) {
  const int idx = blockIdx.x;        // 0..1023
  const int j = idx >> 6;            // 0..15
  const int c = j & 3, kcl = j >> 2;
  const int qt = (kcl == 0) ? 15 - c : (kcl == 1) ? 7 - c : (kcl == 2) ? 8 + c : c;
  const int bh = idx & 63;
  const unsigned short* Qh = Qr + (size_t)bh * S_LEN * DHEAD;
  const unsigned short* Kh = Kr + (size_t)bh * S_LEN * DHEAD;
  const unsigned short* Vh = Vt + (size_t)bh * DHEAD * S_LEN;
  __shared__ unsigned short Ks[2][64 * 64]; // [kcol][dh], XOR-swizzled slots
  __shared__ unsigned short Vs[2][64 * 64]; // [dh][kcol], XOR-swizzled slots
  __shared__ unsigned short Pt[4][16 * 64]; // per-wave P^T [q][k], swizzled
  const int t = threadIdx.x, wave = t >> 6, lane = t & 63;
  const int quad = lane >> 4, l16 = lane & 15;
  const int srow = lane >> 3;
  const int gcol = (((lane & 7) ^ srow)) * 8;
  const int rsw = l16 & 7;
  const int q0 = qt * 128;
  const int qrA = q0 + wave * 16 + l16;  // half A row
  const int qrB = qrA + 64;              // half B row

  bf16x8 qfA0 = *(const bf16x8*)(Qh + (size_t)qrA * DHEAD + quad * 8);
  bf16x8 qfA1 = *(const bf16x8*)(Qh + (size_t)qrA * DHEAD + 32 + quad * 8);
  bf16x8 qfB0 = *(const bf16x8*)(Qh + (size_t)qrB * DHEAD + quad * 8);
  bf16x8 qfB1 = *(const bf16x8*)(Qh + (size_t)qrB * DHEAD + 32 + quad * 8);

  f32x4 oA[4] = {}, oB[4] = {};
  float lA = 0.f, lB = 0.f;
  unsigned short* PtW = &Pt[wave][0];
  const int c0 = (quad ^ rsw) << 3;        // kk=0 frag slot
  const int c1 = ((4 + quad) ^ rsw) << 3;  // kk=1 frag slot
  const int q1b = quad >> 1, qlo4 = (quad & 1) * 4;
  const int pr = l16 * 64;

  auto stage = [&](int kt, int buf) {
    const int k0 = kt * 64;
#pragma unroll
    for (int i = 0; i < 2; i++) {
      async16(Kh + (size_t)(k0 + wave * 16 + i * 8 + srow) * DHEAD + gcol,
              &Ks[buf][(wave * 16 + i * 8) * 64]);
      async16(Vh + (size_t)(wave * 16 + i * 8 + srow) * S_LEN + k0 + gcol,
              &Vs[buf][(wave * 16 + i * 8) * 64]);
    }
  };

  // softmax (no running max: scores bounded) + P^T pack + PV accumulate
  auto softpv = [&](const unsigned short* V_, f32x4* sc, f32x4* o, float& l,
                    int qr_, bool diag, int k0) {
#pragma unroll
    for (int nt = 0; nt < 4; nt++) {
      float p0, p1, p2, p3;
      if (diag) {
        int kg = k0 + nt * 16 + quad * 4;
        p0 = (kg + 0 > qr_) ? 0.f : exp2f(sc[nt][0]);
        p1 = (kg + 1 > qr_) ? 0.f : exp2f(sc[nt][1]);
        p2 = (kg + 2 > qr_) ? 0.f : exp2f(sc[nt][2]);
        p3 = (kg + 3 > qr_) ? 0.f : exp2f(sc[nt][3]);
      } else {
        p0 = exp2f(sc[nt][0]);
        p1 = exp2f(sc[nt][1]);
        p2 = exp2f(sc[nt][2]);
        p3 = exp2f(sc[nt][3]);
      }
      l += (p0 + p1) + (p2 + p3);
      uint2 w; w.x = pkrn(p0, p1); w.y = pkrn(p2, p3);
      const int slot = ((nt * 2 + q1b) ^ rsw) << 3; // nt literal; XOR != dist over +
      *(uint2*)&PtW[pr + slot + qlo4] = w;
    }
#pragma unroll
    for (int kk = 0; kk < 2; kk++) {
      bf16x8 pb = *(const bf16x8*)&PtW[pr + (((kk * 4 + quad) ^ rsw) << 3)];
#pragma unroll
      for (int nt = 0; nt < 4; nt++) {
        bf16x8 vb = *(const bf16x8*)&V_[(nt * 16 + l16) * 64 + (kk == 0 ? c0 : c1)];
        o[nt] = MFMA16(vb, pb, o[nt]);
      }
    }
  };

  // both halves against one tile; K-frags read once from LDS
  auto computeAB = [&](int cur, int k0, bool adiag) {
    const unsigned short* K_ = Ks[cur];
    const unsigned short* V_ = Vs[cur];
    f32x4 scA[4] = {}, scB[4] = {};
#pragma unroll
    for (int nt = 0; nt < 4; nt++) {
      bf16x8 kb0 = *(const bf16x8*)&K_[(nt * 16 + l16) * 64 + c0];
      bf16x8 kb1 = *(const bf16x8*)&K_[(nt * 16 + l16) * 64 + c1];
      scA[nt] = MFMA16(kb0, qfA0, scA[nt]);
      scA[nt] = MFMA16(kb1, qfA1, scA[nt]);
      scB[nt] = MFMA16(kb0, qfB0, scB[nt]);
      scB[nt] = MFMA16(kb1, qfB1, scB[nt]);
    }
    softpv(V_, scA, oA, lA, qrA, adiag, k0);
    softpv(V_, scB, oB, lB, qrB, false, k0);
  };

  stage(0, 0);
  const int kmax = 2 * qt; // A's diagonal tile index; B diag at kmax+1
  int kt = 0;
  for (; kt < kmax; kt += 2) {
    __syncthreads();
    stage(kt + 1, 1);
    computeAB(0, kt * 64, false);
    __syncthreads();
    stage(kt + 2, 0);
    computeAB(1, (kt + 1) * 64, false);
  }
  // kt == kmax (even), buf0 holds tile kmax
  __syncthreads();
  stage(kmax + 1, 1);
  computeAB(0, kmax * 64, true); // A diag-masked, B full
  __syncthreads();
  { // B diagonal tile (buf1): B only
    const unsigned short* K_ = Ks[1];
    const unsigned short* V_ = Vs[1];
    f32x4 scB[4] = {};
#pragma unroll
    for (int nt = 0; nt < 4; nt++) {
      bf16x8 kb0 = *(const bf16x8*)&K_[(nt * 16 + l16) * 64 + c0];
      bf16x8 kb1 = *(const bf16x8*)&K_[(nt * 16 + l16) * 64 + c1];
      scB[nt] = MFMA16(kb0, qfB0, scB[nt]);
      scB[nt] = MFMA16(kb1, qfB1, scB[nt]);
    }
    softpv(V_, scB, oB, lB, qrB, true, (kmax + 1) * 64);
  }

  lA += __shfl_xor(lA, 16); lA += __shfl_xor(lA, 32);
  lB += __shfl_xor(lB, 16); lB += __shfl_xor(lB, 32);
  const float ivA = 1.0f / lA, ivB = 1.0f / lB;
  const int b = bh >> 4, h = bh & 15;
  unsigned short* dA = Xat + (size_t)(b * S_LEN + qrA) * DMODEL + h * DHEAD;
  unsigned short* dB = Xat + (size_t)(b * S_LEN + qrB) * DMODEL + h * DHEAD;
#pragma unroll
  for (int nt = 0; nt < 4; nt++) {
    ushort4 wa, wb;
    wa.x = f2b(oA[nt][0] * ivA); wa.y = f2b(oA[nt][1] * ivA);
    wa.z = f2b(oA[nt][2] * ivA); wa.w = f2b(oA[nt][3] * ivA);
    wb.x = f2b(oB[nt][0] * ivB); wb.y = f2b(oB[nt][1] * ivB);
    wb.z = f2b(oB[nt][2] * ivB); wb.w = f2b(oB[nt][3] * ivB);
    *(ushort4*)(dA + nt * 16 + quad * 4) = wa;
    *(ushort4*)(dB + nt * 16 + quad * 4) = wb;
  }
}

extern "C" void kernel_launch(void* const* d_in, const int* in_sizes, int n_in,
                              void* d_out, int out_size, void* d_ws, size_t ws_size,
                              hipStream_t stream) {
  const float* x = (const float*)d_in[0];
  const float* wq = (const float*)d_in[1];
  const float* wk = (const float*)d_in[2];
  const float* wv = (const float*)d_in[3];
  const float* wo = (const float*)d_in[4];
  const int* pos = (const int*)d_in[5];
  float* out = (float*)d_out;
  char* ws = (char*)d_ws;

  const size_t EL_X = (size_t)MROWS * DMODEL; // 8M elements
  const size_t EL_W = (size_t)DMODEL * DMODEL;
  unsigned short* Xb = (unsigned short*)ws; // bf16 activations [M,K]
  unsigned short* Wqkv = Xb + EL_X;         // [3072][1024] stacked q,k,v
  unsigned short* WoT = Wqkv + 3 * EL_W;
  unsigned short* Qr = WoT + EL_W;  // [b,h,s,dh] roped, pre-scaled
  unsigned short* Kr = Qr + EL_X;   // [b,h,s,dh] roped
  unsigned short* Vt = Kr + EL_X;   // [b,h,dh,s]
  unsigned short* Xat = Vt + EL_X;  // [b,s,h,dh] attention output

  PrepArgs pa;
  pa.x = (const float4*)x; pa.xb = Xb;
  pa.n4 = (int)(EL_X / 4);
  pa.cvtBlocks = (int)(EL_X / 4 / 256); // 8192
  pa.s[0] = wq; pa.d[0] = Wqkv;
  pa.s[1] = wk; pa.d[1] = Wqkv + EL_W;
  pa.s[2] = wv; pa.d[2] = Wqkv + 2 * EL_W;
  pa.s[3] = wo; pa.d[3] = WoT;
  prep_kernel<<<pa.cvtBlocks + 1024, 256, 0, stream>>>(pa);

  dim3 gq(24, 64); // N=3072/128, M=8192/128
  gemm_qkv<<<gq, 256, 0, stream>>>(Xb, Wqkv, Qr, Kr, Vt, pos);
  flash_kernel<<<1024, 256, 0, stream>>>(Qr, Kr, Vt, Xat);
  dim3 gg(8, 64);
  gemm_out<<<gg, 256, 0, stream>>>(Xat, WoT, out);
}

// Round 5
// 280.385 us; speedup vs baseline: 1.1032x; 1.0249x over previous
//
#include <hip/hip_runtime.h>
#include <stdint.h>
#include <math.h>

#define S_LEN 2048
#define DMODEL 1024
#define NHEAD 16
#define DHEAD 64
#define BATCH 4
#define MROWS (BATCH * S_LEN) // 8192

typedef __attribute__((ext_vector_type(8))) short bf16x8;
typedef __attribute__((ext_vector_type(4))) float f32x4;

#define MFMA16(a, b, c) __builtin_amdgcn_mfma_f32_16x16x32_bf16(a, b, c, 0, 0, 0)

__device__ __forceinline__ unsigned short f2b(float f) {
  union { float f; unsigned u; } v; v.f = f;
  unsigned u = v.u;
  return (unsigned short)((u + 0x7FFFu + ((u >> 16) & 1u)) >> 16);
}
// pack two f32 -> bf16x2 in ONE VALU op (RNE); replaces 3-op pkrn. lo=a, hi=b.
__device__ __forceinline__ unsigned cvtpk(float a, float b) {
  unsigned r;
  asm("v_cvt_pk_bf16_f32 %0, %1, %2" : "=v"(r) : "v"(a), "v"(b));
  return r;
}

// async global->LDS, 16B per lane; LDS dest = uniform base + lane*16
__device__ __forceinline__ void async16(const void* g, void* l) {
  __builtin_amdgcn_global_load_lds((const __attribute__((address_space(1))) void*)g,
                                   (__attribute__((address_space(3))) void*)l,
                                   16, 0, 0);
}

// ---------------- fused prep: f32->bf16 cvt (Xb) + 4x 1024x1024 transpose ---
struct PrepArgs {
  const float4* x; unsigned short* xb; int n4; int cvtBlocks;
  const float* s[4]; unsigned short* d[4];
};
__global__ __launch_bounds__(256) void prep_kernel(PrepArgs p) {
  __shared__ float T[64][65];
  const int bid = blockIdx.x;
  const int t = threadIdx.x;
  if (bid < p.cvtBlocks) {
    int i = bid * 256 + t;
    if (i < p.n4) {
      float4 v = p.x[i];
      ushort4 o;
      o.x = f2b(v.x); o.y = f2b(v.y); o.z = f2b(v.z); o.w = f2b(v.w);
      *(ushort4*)(p.xb + 4 * (size_t)i) = o;
    }
    return;
  }
  const int tb = bid - p.cvtBlocks;
  const int z = tb >> 8;
  const int rem = tb & 255;
  const int r0 = (rem >> 4) * 64, c0 = (rem & 15) * 64;
  const float* in = p.s[z];
  unsigned short* out = p.d[z];
  int c = t & 63, rr = t >> 6;
#pragma unroll
  for (int i = 0; i < 16; i++) {
    int r = i * 4 + rr;
    T[r][c] = in[(size_t)(r0 + r) * 1024 + c0 + c];
  }
  __syncthreads();
  int r2 = t & 63, cc = t >> 6;
#pragma unroll
  for (int i = 0; i < 16; i++) {
    int c2 = i * 4 + cc;
    out[(size_t)(c0 + c2) * 1024 + r0 + r2] = f2b(T[r2][c2]);
  }
}

// ---------------- fused QKV GEMM: C[8192,3072] = Xb * Wqkv^T -----------------
// PROVEN 128^2 2-barrier structure (72.8us, 708 TF, MfmaUtil 29).
// R3's 256^2 8-phase port REGRESSED to 92us; needs the exact HK
// barrier/residency placement (m152) -- do not re-attempt naively.
__global__ __launch_bounds__(256) void gemm_qkv(const unsigned short* __restrict__ A,
                                                const unsigned short* __restrict__ Bt,
                                                unsigned short* __restrict__ Qr,
                                                unsigned short* __restrict__ Kr,
                                                unsigned short* __restrict__ Vt,
                                                const int* __restrict__ pos) {
  constexpr int K = 1024;
  __shared__ unsigned short As[128 * 64];
  __shared__ unsigned short Bs[128 * 64];
  const int bm = blockIdx.y * 128, bn = blockIdx.x * 128;
  const int t = threadIdx.x;
  const int wave = t >> 6, lane = t & 63, quad = lane >> 4, l16 = lane & 15;
  const int wm = (wave >> 1) * 64, wn = (wave & 1) * 64;
  f32x4 acc[4][4] = {};
  const int srow = lane >> 3;
  const int gcol = (((lane & 7) ^ srow)) * 8; // XOR-swizzled source column
  const unsigned short* Ag = A + (size_t)(bm + wave * 32 + srow) * K + gcol;
  const unsigned short* Bg = Bt + (size_t)(bn + wave * 32 + srow) * K + gcol;
  unsigned short* AsW = &As[(wave * 32) * 64];
  unsigned short* BsW = &Bs[(wave * 32) * 64];
  const int rsw = l16 & 7;

  for (int k0 = 0; k0 < K; k0 += 64) {
    __syncthreads();
#pragma unroll
    for (int i = 0; i < 4; i++) {
      async16(Ag + (size_t)(i * 8) * K + k0, AsW + i * 8 * 64);
      async16(Bg + (size_t)(i * 8) * K + k0, BsW + i * 8 * 64);
    }
    __syncthreads();
#pragma unroll
    for (int kk = 0; kk < 2; kk++) {
      const int sl = ((kk * 4 + quad) ^ rsw) << 3;
      bf16x8 af[4], bfr[4];
#pragma unroll
      for (int mt = 0; mt < 4; mt++)
        af[mt] = *(const bf16x8*)&As[(wm + mt * 16 + l16) * 64 + sl];
#pragma unroll
      for (int nt = 0; nt < 4; nt++)
        bfr[nt] = *(const bf16x8*)&Bs[(wn + nt * 16 + l16) * 64 + sl];
#pragma unroll
      for (int mt = 0; mt < 4; mt++)
#pragma unroll
        for (int nt = 0; nt < 4; nt++)
          acc[mt][nt] = MFMA16(af[mt], bfr[nt], acc[mt][nt]);
    }
  }

  const int cb = bn + wn;
  if (cb >= 2048) {
    // V: write directly transposed [b,h,dh,s]
    const int h = (cb - 2048) >> 6;
#pragma unroll
    for (int mt = 0; mt < 4; mt++)
#pragma unroll
      for (int nt = 0; nt < 4; nt++) {
        int row = bm + wm + mt * 16 + quad * 4;
        int b = row >> 11, s = row & (S_LEN - 1);
        int dh = nt * 16 + l16;
        ushort4 w4;
        w4.x = f2b(acc[mt][nt][0]); w4.y = f2b(acc[mt][nt][1]);
        w4.z = f2b(acc[mt][nt][2]); w4.w = f2b(acc[mt][nt][3]);
        *(ushort4*)&Vt[((size_t)(b * NHEAD + h) * DHEAD + dh) * S_LEN + s] = w4;
      }
  } else {
    const bool isQ = cb < 1024;
    unsigned short* dst0 = isQ ? Qr : Kr;
    const float scl = isQ ? 0.18033688011112042f : 1.0f; // 0.125*log2(e) for Q
    const int h = (cb >> 6) & 15;
    const float LT = 0.28782313662425572f; // ln(10000)/32
    float it0 = __expf(-(float)l16 * LT);
    float it1 = __expf(-(float)(16 + l16) * LT);
#pragma unroll
    for (int mt = 0; mt < 4; mt++) {
#pragma unroll
      for (int r = 0; r < 4; r++) {
        int row = bm + wm + mt * 16 + quad * 4 + r;
        int b = row >> 11, s = row & (S_LEN - 1);
        float p = (float)pos[row];
        // fast HW sin/cos: arg<=2047 rad, reduction error ~1e-4 << bf16
        // storage error. libm sincosf cost ~= the whole MFMA loop (R6).
        float a0 = p * it0, a1 = p * it1;
        float sn0 = __sinf(a0), cs0 = __cosf(a0);
        float sn1 = __sinf(a1), cs1 = __cosf(a1);
        float x0 = acc[mt][0][r], x1 = acc[mt][1][r];
        float x2 = acc[mt][2][r], x3 = acc[mt][3][r];
        float o0 = (x0 * cs0 - x2 * sn0) * scl;
        float o2 = (x2 * cs0 + x0 * sn0) * scl;
        float o1 = (x1 * cs1 - x3 * sn1) * scl;
        float o3 = (x3 * cs1 + x1 * sn1) * scl;
        unsigned short* dst =
            dst0 + ((size_t)(b * NHEAD + h) * S_LEN + s) * DHEAD;
        dst[0 * 16 + l16] = f2b(o0);
        dst[1 * 16 + l16] = f2b(o1);
        dst[2 * 16 + l16] = f2b(o2);
        dst[3 * 16 + l16] = f2b(o3);
      }
    }
  }
}

// ---------------- out-proj GEMM: out[8192,1024] f32 = Xat * WoT^T -----------
__global__ __launch_bounds__(256) void gemm_out(const unsigned short* __restrict__ A,
                                                const unsigned short* __restrict__ Bt,
                                                float* __restrict__ C) {
  constexpr int K = 1024, N = 1024;
  __shared__ unsigned short As[128 * 64];
  __shared__ unsigned short Bs[128 * 64];
  const int bm = blockIdx.y * 128, bn = blockIdx.x * 128;
  const int t = threadIdx.x;
  const int wave = t >> 6, lane = t & 63, quad = lane >> 4, l16 = lane & 15;
  const int wm = (wave >> 1) * 64, wn = (wave & 1) * 64;
  f32x4 acc[4][4] = {};
  const int srow = lane >> 3;
  const int gcol = (((lane & 7) ^ srow)) * 8;
  const unsigned short* Ag = A + (size_t)(bm + wave * 32 + srow) * K + gcol;
  const unsigned short* Bg = Bt + (size_t)(bn + wave * 32 + srow) * K + gcol;
  unsigned short* AsW = &As[(wave * 32) * 64];
  unsigned short* BsW = &Bs[(wave * 32) * 64];
  const int rsw = l16 & 7;

  for (int k0 = 0; k0 < K; k0 += 64) {
    __syncthreads();
#pragma unroll
    for (int i = 0; i < 4; i++) {
      async16(Ag + (size_t)(i * 8) * K + k0, AsW + i * 8 * 64);
      async16(Bg + (size_t)(i * 8) * K + k0, BsW + i * 8 * 64);
    }
    __syncthreads();
#pragma unroll
    for (int kk = 0; kk < 2; kk++) {
      const int sl = ((kk * 4 + quad) ^ rsw) << 3;
      bf16x8 af[4], bfr[4];
#pragma unroll
      for (int mt = 0; mt < 4; mt++)
        af[mt] = *(const bf16x8*)&As[(wm + mt * 16 + l16) * 64 + sl];
#pragma unroll
      for (int nt = 0; nt < 4; nt++)
        bfr[nt] = *(const bf16x8*)&Bs[(wn + nt * 16 + l16) * 64 + sl];
#pragma unroll
      for (int mt = 0; mt < 4; mt++)
#pragma unroll
        for (int nt = 0; nt < 4; nt++)
          acc[mt][nt] = MFMA16(af[mt], bfr[nt], acc[mt][nt]);
    }
  }
#pragma unroll
  for (int mt = 0; mt < 4; mt++)
#pragma unroll
    for (int nt = 0; nt < 4; nt++)
#pragma unroll
      for (int r = 0; r < 4; r++) {
        int row = bm + wm + mt * 16 + quad * 4 + r;
        int col = bn + wn + nt * 16 + l16;
        C[(size_t)row * N + col] = acc[mt][nt][r];
      }
}

// ---------------- flash attention: 128 q-rows/block (two 64-row halves) -----
// Adjacent pairing. Balance experiments CLOSED: R1 (j,31-j) pairing -> 87us
// (+44% staging); R4 balanced qt permutation -> identical 72.9us. Flash is
// ISSUE-PORT-bound (VALU 55% + MFMA 19% + LDS ~= 80% of slots), not
// imbalance-bound. R5: VALU trim -- (a) pkrn(3 ops) -> v_cvt_pk_bf16_f32
// (1 op); (b) l-sum moved to matrix pipe via ones-MFMA (kills 24 adds/tile +
// final shuffles; C col=l16=q matches epilogue lane ownership; l now sums the
// same bf16-rounded P that PV consumes -- self-consistent softmax).
__global__ __launch_bounds__(256, 3) void flash_kernel(const unsigned short* __restrict__ Qr,
                                                       const unsigned short* __restrict__ Kr,
                                                       const unsigned short* __restrict__ Vt,
                                                       unsigned short* __restrict__ Xat) {
  const int idx = blockIdx.x;        // 0..1023
  const int j = idx >> 6;            // 0..15
  const int c = j & 3, kcl = j >> 2;
  const int qt = (kcl == 0) ? 15 - c : (kcl == 1) ? 7 - c : (kcl == 2) ? 8 + c : c;
  const int bh = idx & 63;
  const unsigned short* Qh = Qr + (size_t)bh * S_LEN * DHEAD;
  const unsigned short* Kh = Kr + (size_t)bh * S_LEN * DHEAD;
  const unsigned short* Vh = Vt + (size_t)bh * DHEAD * S_LEN;
  __shared__ unsigned short Ks[2][64 * 64]; // [kcol][dh], XOR-swizzled slots
  __shared__ unsigned short Vs[2][64 * 64]; // [dh][kcol], XOR-swizzled slots
  __shared__ unsigned short Pt[4][16 * 64]; // per-wave P^T [q][k], swizzled
  const int t = threadIdx.x, wave = t >> 6, lane = t & 63;
  const int quad = lane >> 4, l16 = lane & 15;
  const int srow = lane >> 3;
  const int gcol = (((lane & 7) ^ srow)) * 8;
  const int rsw = l16 & 7;
  const int q0 = qt * 128;
  const int qrA = q0 + wave * 16 + l16;  // half A row
  const int qrB = qrA + 64;              // half B row

  bf16x8 qfA0 = *(const bf16x8*)(Qh + (size_t)qrA * DHEAD + quad * 8);
  bf16x8 qfA1 = *(const bf16x8*)(Qh + (size_t)qrA * DHEAD + 32 + quad * 8);
  bf16x8 qfB0 = *(const bf16x8*)(Qh + (size_t)qrB * DHEAD + quad * 8);
  bf16x8 qfB1 = *(const bf16x8*)(Qh + (size_t)qrB * DHEAD + 32 + quad * 8);

  f32x4 oA[4] = {}, oB[4] = {};
  f32x4 lsA = {}, lsB = {};  // row-sum accumulators (ones-MFMA); lane's q=l16
  bf16x8 onesf;
#pragma unroll
  for (int i = 0; i < 8; i++) onesf[i] = (short)0x3F80; // bf16 1.0
  unsigned short* PtW = &Pt[wave][0];
  const int c0 = (quad ^ rsw) << 3;        // kk=0 frag slot
  const int c1 = ((4 + quad) ^ rsw) << 3;  // kk=1 frag slot
  const int q1b = quad >> 1, qlo4 = (quad & 1) * 4;
  const int pr = l16 * 64;

  auto stage = [&](int kt, int buf) {
    const int k0 = kt * 64;
#pragma unroll
    for (int i = 0; i < 2; i++) {
      async16(Kh + (size_t)(k0 + wave * 16 + i * 8 + srow) * DHEAD + gcol,
              &Ks[buf][(wave * 16 + i * 8) * 64]);
      async16(Vh + (size_t)(wave * 16 + i * 8 + srow) * S_LEN + k0 + gcol,
              &Vs[buf][(wave * 16 + i * 8) * 64]);
    }
  };

  // softmax (no running max: scores bounded) + P^T pack + PV accumulate.
  // Row-sum l via ones-MFMA: ls = 1*P^T + ls -> C[r][q]=sum_k P^T[k][q],
  // identical across r; lane's col = l16 = its q. Replaces 24 VALU adds
  // + 4 end shuffles with 2 MFMA on the 19%-idle matrix pipe.
  auto softpv = [&](const unsigned short* V_, f32x4* sc, f32x4* o, f32x4& ls,
                    int qr_, bool diag, int k0) {
#pragma unroll
    for (int nt = 0; nt < 4; nt++) {
      float p0, p1, p2, p3;
      if (diag) {
        int kg = k0 + nt * 16 + quad * 4;
        p0 = (kg + 0 > qr_) ? 0.f : exp2f(sc[nt][0]);
        p1 = (kg + 1 > qr_) ? 0.f : exp2f(sc[nt][1]);
        p2 = (kg + 2 > qr_) ? 0.f : exp2f(sc[nt][2]);
        p3 = (kg + 3 > qr_) ? 0.f : exp2f(sc[nt][3]);
      } else {
        p0 = exp2f(sc[nt][0]);
        p1 = exp2f(sc[nt][1]);
        p2 = exp2f(sc[nt][2]);
        p3 = exp2f(sc[nt][3]);
      }
      uint2 w; w.x = cvtpk(p0, p1); w.y = cvtpk(p2, p3);
      const int slot = ((nt * 2 + q1b) ^ rsw) << 3; // nt literal; XOR != dist over +
      *(uint2*)&PtW[pr + slot + qlo4] = w;
    }
#pragma unroll
    for (int kk = 0; kk < 2; kk++) {
      bf16x8 pb = *(const bf16x8*)&PtW[pr + (((kk * 4 + quad) ^ rsw) << 3)];
      ls = MFMA16(onesf, pb, ls);
#pragma unroll
      for (int nt = 0; nt < 4; nt++) {
        bf16x8 vb = *(const bf16x8*)&V_[(nt * 16 + l16) * 64 + (kk == 0 ? c0 : c1)];
        o[nt] = MFMA16(vb, pb, o[nt]);
      }
    }
  };

  // both halves against one tile; K-frags read once from LDS
  auto computeAB = [&](int cur, int k0, bool adiag) {
    const unsigned short* K_ = Ks[cur];
    const unsigned short* V_ = Vs[cur];
    f32x4 scA[4] = {}, scB[4] = {};
#pragma unroll
    for (int nt = 0; nt < 4; nt++) {
      bf16x8 kb0 = *(const bf16x8*)&K_[(nt * 16 + l16) * 64 + c0];
      bf16x8 kb1 = *(const bf16x8*)&K_[(nt * 16 + l16) * 64 + c1];
      scA[nt] = MFMA16(kb0, qfA0, scA[nt]);
      scA[nt] = MFMA16(kb1, qfA1, scA[nt]);
      scB[nt] = MFMA16(kb0, qfB0, scB[nt]);
      scB[nt] = MFMA16(kb1, qfB1, scB[nt]);
    }
    softpv(V_, scA, oA, lsA, qrA, adiag, k0);
    softpv(V_, scB, oB, lsB, qrB, false, k0);
  };

  stage(0, 0);
  const int kmax = 2 * qt; // A's diagonal tile index; B diag at kmax+1
  int kt = 0;
  for (; kt < kmax; kt += 2) {
    __syncthreads();
    stage(kt + 1, 1);
    computeAB(0, kt * 64, false);
    __syncthreads();
    stage(kt + 2, 0);
    computeAB(1, (kt + 1) * 64, false);
  }
  // kt == kmax (even), buf0 holds tile kmax
  __syncthreads();
  stage(kmax + 1, 1);
  computeAB(0, kmax * 64, true); // A diag-masked, B full
  __syncthreads();
  { // B diagonal tile (buf1): B only
    const unsigned short* K_ = Ks[1];
    const unsigned short* V_ = Vs[1];
    f32x4 scB[4] = {};
#pragma unroll
    for (int nt = 0; nt < 4; nt++) {
      bf16x8 kb0 = *(const bf16x8*)&K_[(nt * 16 + l16) * 64 + c0];
      bf16x8 kb1 = *(const bf16x8*)&K_[(nt * 16 + l16) * 64 + c1];
      scB[nt] = MFMA16(kb0, qfB0, scB[nt]);
      scB[nt] = MFMA16(kb1, qfB1, scB[nt]);
    }
    softpv(V_, scB, oB, lsB, qrB, true, (kmax + 1) * 64);
  }

  const float ivA = 1.0f / lsA[0], ivB = 1.0f / lsB[0];
  const int b = bh >> 4, h = bh & 15;
  unsigned short* dA = Xat + (size_t)(b * S_LEN + qrA) * DMODEL + h * DHEAD;
  unsigned short* dB = Xat + (size_t)(b * S_LEN + qrB) * DMODEL + h * DHEAD;
#pragma unroll
  for (int nt = 0; nt < 4; nt++) {
    ushort4 wa, wb;
    wa.x = f2b(oA[nt][0] * ivA); wa.y = f2b(oA[nt][1] * ivA);
    wa.z = f2b(oA[nt][2] * ivA); wa.w = f2b(oA[nt][3] * ivA);
    wb.x = f2b(oB[nt][0] * ivB); wb.y = f2b(oB[nt][1] * ivB);
    wb.z = f2b(oB[nt][2] * ivB); wb.w = f2b(oB[nt][3] * ivB);
    *(ushort4*)(dA + nt * 16 + quad * 4) = wa;
    *(ushort4*)(dB + nt * 16 + quad * 4) = wb;
  }
}

extern "C" void kernel_launch(void* const* d_in, const int* in_sizes, int n_in,
                              void* d_out, int out_size, void* d_ws, size_t ws_size,
                              hipStream_t stream) {
  const float* x = (const float*)d_in[0];
  const float* wq = (const float*)d_in[1];
  const float* wk = (const float*)d_in[2];
  const float* wv = (const float*)d_in[3];
  const float* wo = (const float*)d_in[4];
  const int* pos = (const int*)d_in[5];
  float* out = (float*)d_out;
  char* ws = (char*)d_ws;

  const size_t EL_X = (size_t)MROWS * DMODEL; // 8M elements
  const size_t EL_W = (size_t)DMODEL * DMODEL;
  unsigned short* Xb = (unsigned short*)ws; // bf16 activations [M,K]
  unsigned short* Wqkv = Xb + EL_X;         // [3072][1024] stacked q,k,v
  unsigned short* WoT = Wqkv + 3 * EL_W;
  unsigned short* Qr = WoT + EL_W;  // [b,h,s,dh] roped, pre-scaled
  unsigned short* Kr = Qr + EL_X;   // [b,h,s,dh] roped
  unsigned short* Vt = Kr + EL_X;   // [b,h,dh,s]
  unsigned short* Xat = Vt + EL_X;  // [b,s,h,dh] attention output

  PrepArgs pa;
  pa.x = (const float4*)x; pa.xb = Xb;
  pa.n4 = (int)(EL_X / 4);
  pa.cvtBlocks = (int)(EL_X / 4 / 256); // 8192
  pa.s[0] = wq; pa.d[0] = Wqkv;
  pa.s[1] = wk; pa.d[1] = Wqkv + EL_W;
  pa.s[2] = wv; pa.d[2] = Wqkv + 2 * EL_W;
  pa.s[3] = wo; pa.d[3] = WoT;
  prep_kernel<<<pa.cvtBlocks + 1024, 256, 0, stream>>>(pa);

  dim3 gq(24, 64); // N=3072/128, M=8192/128
  gemm_qkv<<<gq, 256, 0, stream>>>(Xb, Wqkv, Qr, Kr, Vt, pos);
  flash_kernel<<<1024, 256, 0, stream>>>(Qr, Kr, Vt, Xat);
  dim3 gg(8, 64);
  gemm_out<<<gg, 256, 0, stream>>>(Xat, WoT, out);
}

// Round 6
// 279.444 us; speedup vs baseline: 1.1069x; 1.0034x over previous
//
#include <hip/hip_runtime.h>
#include <stdint.h>
#include <math.h>

#define S_LEN 2048
#define DMODEL 1024
#define NHEAD 16
#define DHEAD 64
#define BATCH 4
#define MROWS (BATCH * S_LEN) // 8192

typedef __attribute__((ext_vector_type(8))) short bf16x8;
typedef __attribute__((ext_vector_type(4))) float f32x4;

#define MFMA16(a, b, c) __builtin_amdgcn_mfma_f32_16x16x32_bf16(a, b, c, 0, 0, 0)

__device__ __forceinline__ unsigned short f2b(float f) {
  union { float f; unsigned u; } v; v.f = f;
  unsigned u = v.u;
  return (unsigned short)((u + 0x7FFFu + ((u >> 16) & 1u)) >> 16);
}
// pack two f32 -> bf16x2 in ONE VALU op (RNE); replaces 3-op pkrn. lo=a, hi=b.
__device__ __forceinline__ unsigned cvtpk(float a, float b) {
  unsigned r;
  asm("v_cvt_pk_bf16_f32 %0, %1, %2" : "=v"(r) : "v"(a), "v"(b));
  return r;
}

// async global->LDS, 16B per lane; LDS dest = uniform base + lane*16
__device__ __forceinline__ void async16(const void* g, void* l) {
  __builtin_amdgcn_global_load_lds((const __attribute__((address_space(1))) void*)g,
                                   (__attribute__((address_space(3))) void*)l,
                                   16, 0, 0);
}

// ---------------- fused prep: f32->bf16 cvt (Xb) + 4x 1024x1024 transpose ---
struct PrepArgs {
  const float4* x; unsigned short* xb; int n4; int cvtBlocks;
  const float* s[4]; unsigned short* d[4];
};
__global__ __launch_bounds__(256) void prep_kernel(PrepArgs p) {
  __shared__ float T[64][65];
  const int bid = blockIdx.x;
  const int t = threadIdx.x;
  if (bid < p.cvtBlocks) {
    int i = bid * 256 + t;
    if (i < p.n4) {
      float4 v = p.x[i];
      ushort4 o;
      o.x = f2b(v.x); o.y = f2b(v.y); o.z = f2b(v.z); o.w = f2b(v.w);
      *(ushort4*)(p.xb + 4 * (size_t)i) = o;
    }
    return;
  }
  const int tb = bid - p.cvtBlocks;
  const int z = tb >> 8;
  const int rem = tb & 255;
  const int r0 = (rem >> 4) * 64, c0 = (rem & 15) * 64;
  const float* in = p.s[z];
  unsigned short* out = p.d[z];
  int c = t & 63, rr = t >> 6;
#pragma unroll
  for (int i = 0; i < 16; i++) {
    int r = i * 4 + rr;
    T[r][c] = in[(size_t)(r0 + r) * 1024 + c0 + c];
  }
  __syncthreads();
  int r2 = t & 63, cc = t >> 6;
#pragma unroll
  for (int i = 0; i < 16; i++) {
    int c2 = i * 4 + cc;
    out[(size_t)(c0 + c2) * 1024 + r0 + r2] = f2b(T[r2][c2]);
  }
}

// ---------------- fused QKV GEMM: C[8192,3072] = Xb * Wqkv^T -----------------
// PROVEN 128^2 2-barrier structure (72.8us, 708 TF, MfmaUtil 29).
// R3's 256^2 8-phase port REGRESSED to 92us; needs the exact HK
// barrier/residency placement (m152) -- do not re-attempt naively.
__global__ __launch_bounds__(256) void gemm_qkv(const unsigned short* __restrict__ A,
                                                const unsigned short* __restrict__ Bt,
                                                unsigned short* __restrict__ Qr,
                                                unsigned short* __restrict__ Kr,
                                                unsigned short* __restrict__ Vt,
                                                const int* __restrict__ pos) {
  constexpr int K = 1024;
  __shared__ unsigned short As[128 * 64];
  __shared__ unsigned short Bs[128 * 64];
  const int bm = blockIdx.y * 128, bn = blockIdx.x * 128;
  const int t = threadIdx.x;
  const int wave = t >> 6, lane = t & 63, quad = lane >> 4, l16 = lane & 15;
  const int wm = (wave >> 1) * 64, wn = (wave & 1) * 64;
  f32x4 acc[4][4] = {};
  const int srow = lane >> 3;
  const int gcol = (((lane & 7) ^ srow)) * 8; // XOR-swizzled source column
  const unsigned short* Ag = A + (size_t)(bm + wave * 32 + srow) * K + gcol;
  const unsigned short* Bg = Bt + (size_t)(bn + wave * 32 + srow) * K + gcol;
  unsigned short* AsW = &As[(wave * 32) * 64];
  unsigned short* BsW = &Bs[(wave * 32) * 64];
  const int rsw = l16 & 7;

  for (int k0 = 0; k0 < K; k0 += 64) {
    __syncthreads();
#pragma unroll
    for (int i = 0; i < 4; i++) {
      async16(Ag + (size_t)(i * 8) * K + k0, AsW + i * 8 * 64);
      async16(Bg + (size_t)(i * 8) * K + k0, BsW + i * 8 * 64);
    }
    __syncthreads();
#pragma unroll
    for (int kk = 0; kk < 2; kk++) {
      const int sl = ((kk * 4 + quad) ^ rsw) << 3;
      bf16x8 af[4], bfr[4];
#pragma unroll
      for (int mt = 0; mt < 4; mt++)
        af[mt] = *(const bf16x8*)&As[(wm + mt * 16 + l16) * 64 + sl];
#pragma unroll
      for (int nt = 0; nt < 4; nt++)
        bfr[nt] = *(const bf16x8*)&Bs[(wn + nt * 16 + l16) * 64 + sl];
#pragma unroll
      for (int mt = 0; mt < 4; mt++)
#pragma unroll
        for (int nt = 0; nt < 4; nt++)
          acc[mt][nt] = MFMA16(af[mt], bfr[nt], acc[mt][nt]);
    }
  }

  const int cb = bn + wn;
  if (cb >= 2048) {
    // V: write directly transposed [b,h,dh,s]
    const int h = (cb - 2048) >> 6;
#pragma unroll
    for (int mt = 0; mt < 4; mt++)
#pragma unroll
      for (int nt = 0; nt < 4; nt++) {
        int row = bm + wm + mt * 16 + quad * 4;
        int b = row >> 11, s = row & (S_LEN - 1);
        int dh = nt * 16 + l16;
        ushort4 w4;
        w4.x = f2b(acc[mt][nt][0]); w4.y = f2b(acc[mt][nt][1]);
        w4.z = f2b(acc[mt][nt][2]); w4.w = f2b(acc[mt][nt][3]);
        *(ushort4*)&Vt[((size_t)(b * NHEAD + h) * DHEAD + dh) * S_LEN + s] = w4;
      }
  } else {
    const bool isQ = cb < 1024;
    unsigned short* dst0 = isQ ? Qr : Kr;
    const float scl = isQ ? 0.18033688011112042f : 1.0f; // 0.125*log2(e) for Q
    const int h = (cb >> 6) & 15;
    const float LT = 0.28782313662425572f; // ln(10000)/32
    float it0 = __expf(-(float)l16 * LT);
    float it1 = __expf(-(float)(16 + l16) * LT);
#pragma unroll
    for (int mt = 0; mt < 4; mt++) {
#pragma unroll
      for (int r = 0; r < 4; r++) {
        int row = bm + wm + mt * 16 + quad * 4 + r;
        int b = row >> 11, s = row & (S_LEN - 1);
        float p = (float)pos[row];
        // fast HW sin/cos: arg<=2047 rad, reduction error ~1e-4 << bf16
        // storage error. libm sincosf cost ~= the whole MFMA loop (R6).
        float a0 = p * it0, a1 = p * it1;
        float sn0 = __sinf(a0), cs0 = __cosf(a0);
        float sn1 = __sinf(a1), cs1 = __cosf(a1);
        float x0 = acc[mt][0][r], x1 = acc[mt][1][r];
        float x2 = acc[mt][2][r], x3 = acc[mt][3][r];
        float o0 = (x0 * cs0 - x2 * sn0) * scl;
        float o2 = (x2 * cs0 + x0 * sn0) * scl;
        float o1 = (x1 * cs1 - x3 * sn1) * scl;
        float o3 = (x3 * cs1 + x1 * sn1) * scl;
        unsigned short* dst =
            dst0 + ((size_t)(b * NHEAD + h) * S_LEN + s) * DHEAD;
        dst[0 * 16 + l16] = f2b(o0);
        dst[1 * 16 + l16] = f2b(o1);
        dst[2 * 16 + l16] = f2b(o2);
        dst[3 * 16 + l16] = f2b(o3);
      }
    }
  }
}

// ---------------- out-proj GEMM: out[8192,1024] f32 = Xat * WoT^T -----------
__global__ __launch_bounds__(256) void gemm_out(const unsigned short* __restrict__ A,
                                                const unsigned short* __restrict__ Bt,
                                                float* __restrict__ C) {
  constexpr int K = 1024, N = 1024;
  __shared__ unsigned short As[128 * 64];
  __shared__ unsigned short Bs[128 * 64];
  const int bm = blockIdx.y * 128, bn = blockIdx.x * 128;
  const int t = threadIdx.x;
  const int wave = t >> 6, lane = t & 63, quad = lane >> 4, l16 = lane & 15;
  const int wm = (wave >> 1) * 64, wn = (wave & 1) * 64;
  f32x4 acc[4][4] = {};
  const int srow = lane >> 3;
  const int gcol = (((lane & 7) ^ srow)) * 8;
  const unsigned short* Ag = A + (size_t)(bm + wave * 32 + srow) * K + gcol;
  const unsigned short* Bg = Bt + (size_t)(bn + wave * 32 + srow) * K + gcol;
  unsigned short* AsW = &As[(wave * 32) * 64];
  unsigned short* BsW = &Bs[(wave * 32) * 64];
  const int rsw = l16 & 7;

  for (int k0 = 0; k0 < K; k0 += 64) {
    __syncthreads();
#pragma unroll
    for (int i = 0; i < 4; i++) {
      async16(Ag + (size_t)(i * 8) * K + k0, AsW + i * 8 * 64);
      async16(Bg + (size_t)(i * 8) * K + k0, BsW + i * 8 * 64);
    }
    __syncthreads();
#pragma unroll
    for (int kk = 0; kk < 2; kk++) {
      const int sl = ((kk * 4 + quad) ^ rsw) << 3;
      bf16x8 af[4], bfr[4];
#pragma unroll
      for (int mt = 0; mt < 4; mt++)
        af[mt] = *(const bf16x8*)&As[(wm + mt * 16 + l16) * 64 + sl];
#pragma unroll
      for (int nt = 0; nt < 4; nt++)
        bfr[nt] = *(const bf16x8*)&Bs[(wn + nt * 16 + l16) * 64 + sl];
#pragma unroll
      for (int mt = 0; mt < 4; mt++)
#pragma unroll
        for (int nt = 0; nt < 4; nt++)
          acc[mt][nt] = MFMA16(af[mt], bfr[nt], acc[mt][nt]);
    }
  }
#pragma unroll
  for (int mt = 0; mt < 4; mt++)
#pragma unroll
    for (int nt = 0; nt < 4; nt++)
#pragma unroll
      for (int r = 0; r < 4; r++) {
        int row = bm + wm + mt * 16 + quad * 4 + r;
        int col = bn + wn + nt * 16 + l16;
        C[(size_t)row * N + col] = acc[mt][nt][r];
      }
}

// ---------------- flash attention: 128 q-rows/block (two 64-row halves) -----
// Issue-port-bound (R4/R5 evidence): VALU trim (cvtpk + ones-MFMA l-sum)
// bought 73->66us. R6: LDS-pipe trim -- V-fragments are half-independent but
// were read TWICE (8 ds_read_b128 per half); hoist to registers once per tile
// and share across both halves: -8 b128 reads/tile (~22% of LDS-pipe issue),
// +32 VGPR (84 -> ~116, under the 170 cap at waves/EU=3; no spill).
__global__ __launch_bounds__(256, 3) void flash_kernel(const unsigned short* __restrict__ Qr,
                                                       const unsigned short* __restrict__ Kr,
                                                       const unsigned short* __restrict__ Vt,
                                                       unsigned short* __restrict__ Xat) {
  const int idx = blockIdx.x;        // 0..1023
  const int j = idx >> 6;            // 0..15
  const int c = j & 3, kcl = j >> 2;
  const int qt = (kcl == 0) ? 15 - c : (kcl == 1) ? 7 - c : (kcl == 2) ? 8 + c : c;
  const int bh = idx & 63;
  const unsigned short* Qh = Qr + (size_t)bh * S_LEN * DHEAD;
  const unsigned short* Kh = Kr + (size_t)bh * S_LEN * DHEAD;
  const unsigned short* Vh = Vt + (size_t)bh * DHEAD * S_LEN;
  __shared__ unsigned short Ks[2][64 * 64]; // [kcol][dh], XOR-swizzled slots
  __shared__ unsigned short Vs[2][64 * 64]; // [dh][kcol], XOR-swizzled slots
  __shared__ unsigned short Pt[4][16 * 64]; // per-wave P^T [q][k], swizzled
  const int t = threadIdx.x, wave = t >> 6, lane = t & 63;
  const int quad = lane >> 4, l16 = lane & 15;
  const int srow = lane >> 3;
  const int gcol = (((lane & 7) ^ srow)) * 8;
  const int rsw = l16 & 7;
  const int q0 = qt * 128;
  const int qrA = q0 + wave * 16 + l16;  // half A row
  const int qrB = qrA + 64;              // half B row

  bf16x8 qfA0 = *(const bf16x8*)(Qh + (size_t)qrA * DHEAD + quad * 8);
  bf16x8 qfA1 = *(const bf16x8*)(Qh + (size_t)qrA * DHEAD + 32 + quad * 8);
  bf16x8 qfB0 = *(const bf16x8*)(Qh + (size_t)qrB * DHEAD + quad * 8);
  bf16x8 qfB1 = *(const bf16x8*)(Qh + (size_t)qrB * DHEAD + 32 + quad * 8);

  f32x4 oA[4] = {}, oB[4] = {};
  f32x4 lsA = {}, lsB = {};  // row-sum accumulators (ones-MFMA); lane's q=l16
  bf16x8 onesf;
#pragma unroll
  for (int i = 0; i < 8; i++) onesf[i] = (short)0x3F80; // bf16 1.0
  unsigned short* PtW = &Pt[wave][0];
  const int c0 = (quad ^ rsw) << 3;        // kk=0 frag slot
  const int c1 = ((4 + quad) ^ rsw) << 3;  // kk=1 frag slot
  const int q1b = quad >> 1, qlo4 = (quad & 1) * 4;
  const int pr = l16 * 64;

  auto stage = [&](int kt, int buf) {
    const int k0 = kt * 64;
#pragma unroll
    for (int i = 0; i < 2; i++) {
      async16(Kh + (size_t)(k0 + wave * 16 + i * 8 + srow) * DHEAD + gcol,
              &Ks[buf][(wave * 16 + i * 8) * 64]);
      async16(Vh + (size_t)(wave * 16 + i * 8 + srow) * S_LEN + k0 + gcol,
              &Vs[buf][(wave * 16 + i * 8) * 64]);
    }
  };

  // softmax (no running max: scores bounded) + P^T pack + PV accumulate.
  // V-frags passed in registers (shared across both halves).
  // Row-sum l via ones-MFMA: lane's col = l16 = its q.
  auto softpv = [&](const bf16x8* vb0, const bf16x8* vb1, f32x4* sc, f32x4* o,
                    f32x4& ls, int qr_, bool diag, int k0) {
#pragma unroll
    for (int nt = 0; nt < 4; nt++) {
      float p0, p1, p2, p3;
      if (diag) {
        int kg = k0 + nt * 16 + quad * 4;
        p0 = (kg + 0 > qr_) ? 0.f : exp2f(sc[nt][0]);
        p1 = (kg + 1 > qr_) ? 0.f : exp2f(sc[nt][1]);
        p2 = (kg + 2 > qr_) ? 0.f : exp2f(sc[nt][2]);
        p3 = (kg + 3 > qr_) ? 0.f : exp2f(sc[nt][3]);
      } else {
        p0 = exp2f(sc[nt][0]);
        p1 = exp2f(sc[nt][1]);
        p2 = exp2f(sc[nt][2]);
        p3 = exp2f(sc[nt][3]);
      }
      uint2 w; w.x = cvtpk(p0, p1); w.y = cvtpk(p2, p3);
      const int slot = ((nt * 2 + q1b) ^ rsw) << 3; // nt literal; XOR != dist over +
      *(uint2*)&PtW[pr + slot + qlo4] = w;
    }
#pragma unroll
    for (int kk = 0; kk < 2; kk++) {
      bf16x8 pb = *(const bf16x8*)&PtW[pr + (((kk * 4 + quad) ^ rsw) << 3)];
      ls = MFMA16(onesf, pb, ls);
      const bf16x8* vb = (kk == 0) ? vb0 : vb1; // kk literal under unroll
#pragma unroll
      for (int nt = 0; nt < 4; nt++) o[nt] = MFMA16(vb[nt], pb, o[nt]);
    }
  };

  // both halves against one tile; K-frags AND V-frags read once from LDS
  auto computeAB = [&](int cur, int k0, bool adiag) {
    const unsigned short* K_ = Ks[cur];
    const unsigned short* V_ = Vs[cur];
    f32x4 scA[4] = {}, scB[4] = {};
    bf16x8 vb0[4], vb1[4];
#pragma unroll
    for (int nt = 0; nt < 4; nt++) {
      bf16x8 kb0 = *(const bf16x8*)&K_[(nt * 16 + l16) * 64 + c0];
      bf16x8 kb1 = *(const bf16x8*)&K_[(nt * 16 + l16) * 64 + c1];
      vb0[nt] = *(const bf16x8*)&V_[(nt * 16 + l16) * 64 + c0];
      vb1[nt] = *(const bf16x8*)&V_[(nt * 16 + l16) * 64 + c1];
      scA[nt] = MFMA16(kb0, qfA0, scA[nt]);
      scA[nt] = MFMA16(kb1, qfA1, scA[nt]);
      scB[nt] = MFMA16(kb0, qfB0, scB[nt]);
      scB[nt] = MFMA16(kb1, qfB1, scB[nt]);
    }
    softpv(vb0, vb1, scA, oA, lsA, qrA, adiag, k0);
    softpv(vb0, vb1, scB, oB, lsB, qrB, false, k0);
  };

  stage(0, 0);
  const int kmax = 2 * qt; // A's diagonal tile index; B diag at kmax+1
  int kt = 0;
  for (; kt < kmax; kt += 2) {
    __syncthreads();
    stage(kt + 1, 1);
    computeAB(0, kt * 64, false);
    __syncthreads();
    stage(kt + 2, 0);
    computeAB(1, (kt + 1) * 64, false);
  }
  // kt == kmax (even), buf0 holds tile kmax
  __syncthreads();
  stage(kmax + 1, 1);
  computeAB(0, kmax * 64, true); // A diag-masked, B full
  __syncthreads();
  { // B diagonal tile (buf1): B only
    const unsigned short* K_ = Ks[1];
    const unsigned short* V_ = Vs[1];
    f32x4 scB[4] = {};
    bf16x8 vb0[4], vb1[4];
#pragma unroll
    for (int nt = 0; nt < 4; nt++) {
      bf16x8 kb0 = *(const bf16x8*)&K_[(nt * 16 + l16) * 64 + c0];
      bf16x8 kb1 = *(const bf16x8*)&K_[(nt * 16 + l16) * 64 + c1];
      vb0[nt] = *(const bf16x8*)&V_[(nt * 16 + l16) * 64 + c0];
      vb1[nt] = *(const bf16x8*)&V_[(nt * 16 + l16) * 64 + c1];
      scB[nt] = MFMA16(kb0, qfB0, scB[nt]);
      scB[nt] = MFMA16(kb1, qfB1, scB[nt]);
    }
    softpv(vb0, vb1, scB, oB, lsB, qrB, true, (kmax + 1) * 64);
  }

  const float ivA = 1.0f / lsA[0], ivB = 1.0f / lsB[0];
  const int b = bh >> 4, h = bh & 15;
  unsigned short* dA = Xat + (size_t)(b * S_LEN + qrA) * DMODEL + h * DHEAD;
  unsigned short* dB = Xat + (size_t)(b * S_LEN + qrB) * DMODEL + h * DHEAD;
#pragma unroll
  for (int nt = 0; nt < 4; nt++) {
    ushort4 wa, wb;
    wa.x = f2b(oA[nt][0] * ivA); wa.y = f2b(oA[nt][1] * ivA);
    wa.z = f2b(oA[nt][2] * ivA); wa.w = f2b(oA[nt][3] * ivA);
    wb.x = f2b(oB[nt][0] * ivB); wb.y = f2b(oB[nt][1] * ivB);
    wb.z = f2b(oB[nt][2] * ivB); wb.w = f2b(oB[nt][3] * ivB);
    *(ushort4*)(dA + nt * 16 + quad * 4) = wa;
    *(ushort4*)(dB + nt * 16 + quad * 4) = wb;
  }
}

extern "C" void kernel_launch(void* const* d_in, const int* in_sizes, int n_in,
                              void* d_out, int out_size, void* d_ws, size_t ws_size,
                              hipStream_t stream) {
  const float* x = (const float*)d_in[0];
  const float* wq = (const float*)d_in[1];
  const float* wk = (const float*)d_in[2];
  const float* wv = (const float*)d_in[3];
  const float* wo = (const float*)d_in[4];
  const int* pos = (const int*)d_in[5];
  float* out = (float*)d_out;
  char* ws = (char*)d_ws;

  const size_t EL_X = (size_t)MROWS * DMODEL; // 8M elements
  const size_t EL_W = (size_t)DMODEL * DMODEL;
  unsigned short* Xb = (unsigned short*)ws; // bf16 activations [M,K]
  unsigned short* Wqkv = Xb + EL_X;         // [3072][1024] stacked q,k,v
  unsigned short* WoT = Wqkv + 3 * EL_W;
  unsigned short* Qr = WoT + EL_W;  // [b,h,s,dh] roped, pre-scaled
  unsigned short* Kr = Qr + EL_X;   // [b,h,s,dh] roped
  unsigned short* Vt = Kr + EL_X;   // [b,h,dh,s]
  unsigned short* Xat = Vt + EL_X;  // [b,s,h,dh] attention output

  PrepArgs pa;
  pa.x = (const float4*)x; pa.xb = Xb;
  pa.n4 = (int)(EL_X / 4);
  pa.cvtBlocks = (int)(EL_X / 4 / 256); // 8192
  pa.s[0] = wq; pa.d[0] = Wqkv;
  pa.s[1] = wk; pa.d[1] = Wqkv + EL_W;
  pa.s[2] = wv; pa.d[2] = Wqkv + 2 * EL_W;
  pa.s[3] = wo; pa.d[3] = WoT;
  prep_kernel<<<pa.cvtBlocks + 1024, 256, 0, stream>>>(pa);

  dim3 gq(24, 64); // N=3072/128, M=8192/128
  gemm_qkv<<<gq, 256, 0, stream>>>(Xb, Wqkv, Qr, Kr, Vt, pos);
  flash_kernel<<<1024, 256, 0, stream>>>(Qr, Kr, Vt, Xat);
  dim3 gg(8, 64);
  gemm_out<<<gg, 256, 0, stream>>>(Xat, WoT, out);
}